// Round 12
// baseline (231.863 us; speedup 1.0000x reference)
//
#include <hip/hip_runtime.h>
#include <math.h>

#define T_SEQ     2048
#define HIDDEN_   2048
#define NUM_HEADS 16
#define NUM_KV    8
#define HEAD_DIM  128
#define Q_SIZE    2048
#define KV_SIZE   1024
#define QKV_N     4096
#define QK_N      3072
#define EPS_      1e-6f

typedef __attribute__((ext_vector_type(8))) short short8;
typedef __attribute__((ext_vector_type(4))) float floatx4;

__device__ __forceinline__ unsigned short f2bf(float f) {
    unsigned int u = __float_as_uint(f);
    u += 0x7fffu + ((u >> 16) & 1u);     // RNE
    return (unsigned short)(u >> 16);
}
__device__ __forceinline__ float b2f(unsigned short u) {
    return __uint_as_float((unsigned int)u << 16);
}

__device__ __forceinline__ void stage16(const unsigned short* g, unsigned short* lds_base) {
    __builtin_amdgcn_global_load_lds(
        (const __attribute__((address_space(1))) unsigned int*)g,
        (__attribute__((address_space(3))) unsigned int*)lds_base, 16, 0, 0);
}

// ---------------------------------------------------------------------------
// Fused fp32 -> bf16 conversion of hidden, qkv_w, o_w in ONE launch.
// ---------------------------------------------------------------------------
#define H4 (T_SEQ * HIDDEN_ / 4)
#define W4 (QKV_N * HIDDEN_ / 4)
#define O4 (Q_SIZE * HIDDEN_ / 4)

__global__ __launch_bounds__(256) void convert_all(
    const float* __restrict__ hidden, const float* __restrict__ qkv_w,
    const float* __restrict__ o_w, unsigned short* __restrict__ hbf,
    unsigned short* __restrict__ wbf, unsigned short* __restrict__ obf)
{
    int i = blockIdx.x * 256 + threadIdx.x;
    const float4* src;
    ushort4* dst;
    int j;
    if (i < H4)            { src = (const float4*)hidden; dst = (ushort4*)hbf; j = i; }
    else if (i < H4 + W4)  { src = (const float4*)qkv_w;  dst = (ushort4*)wbf; j = i - H4; }
    else                   { src = (const float4*)o_w;    dst = (ushort4*)obf; j = i - H4 - W4;
                             if (j >= O4) return; }
    float4 v = src[j];
    ushort4 o;
    o.x = f2bf(v.x); o.y = f2bf(v.y); o.z = f2bf(v.z); o.w = f2bf(v.w);
    dst[j] = o;
}

// ---------------------------------------------------------------------------
// bf16 MFMA GEMM (NT), 128x128 tile, 1024 threads / 16 waves, wave-tile 32x32.
// Counted-vmcnt pipeline (BK=64, dbuf, raw s_barrier, never vmcnt(0)
// mid-loop), hoisted LDS addresses (R19).
// R20: MODE 2 = split-K O-projection. O-proj at 256 blocks was 1 block/CU
// (358 TF = 14% of peak vs QKV's 1.42 PF = 57% — same per-block pipeline
// time for half the FLOPs). blockIdx.z in {0,1} selects a K-half (16
// K-tiles); grid 512 blocks = 2 blocks/CU; fp32 partials summed by
// combine_o below.
// MODE 0: C fp32 row-major (unused in launcher now, kept for reference).
// MODE 1 (QKV): q/k: fused RMSNorm + RoPE epilogue; v: transposed Vt store.
// MODE 2: partial C fp32 to C + z*M*N over K-half z.
// ---------------------------------------------------------------------------
template<int MODE>
__global__ __launch_bounds__(1024, 8) void gemm_nt_bf16(
    const unsigned short* __restrict__ A, const unsigned short* __restrict__ B,
    float* __restrict__ C,
    unsigned short* __restrict__ Qb, unsigned short* __restrict__ Kb,
    unsigned short* __restrict__ Vt,
    const int* __restrict__ positions,
    const float* __restrict__ qw, const float* __restrict__ kw,
    int M, int N, int K)
{
    // smem: As[2][128*64] at 0, Bs[2][128*64] at 16384 (elem offsets). 64 KB.
    __shared__ unsigned short smem[32768];
    unsigned short* const As0 = smem;
    unsigned short* const Bs0 = smem + 16384;

    const int tid  = threadIdx.x;
    const int w    = tid >> 6;           // 0..15
    const int lane = tid & 63;
    const int colL = lane & 15;
    const int quad = lane >> 4;
    const int bm = blockIdx.y * 128;
    const int bn = blockIdx.x * 128;
    const int wr = w >> 2;               // 4 row-groups
    const int wc = w & 3;                // 4 col-groups
    const int wm = wr * 32;
    const int wn = wc * 32;

    floatx4 acc[2][2];
    #pragma unroll
    for (int i = 0; i < 2; ++i)
        #pragma unroll
        for (int j = 0; j < 2; ++j)
            acc[i][j] = (floatx4){0.f, 0.f, 0.f, 0.f};

    // 1024 16B-chunks per matrix per tile; 1024 threads -> 1 chunk each.
    const int s_r  = tid >> 3;
    const int s_lc = (tid & 7) ^ (s_r & 7);

    // ---- K-split (MODE 2): this block covers K-half blockIdx.z ----
    const int koff = (MODE == 2) ? (int)blockIdx.z * (K >> 1) : 0;
    const int nt   = (MODE == 2) ? (K >> 7) : (K >> 6);   // K-tiles (even)

    // ---- Hoisted staging bases (loop-invariant) ----
    const unsigned short* gA = A + (size_t)(bm + s_r) * K + koff + s_lc * 8;
    const unsigned short* gB = B + (size_t)(bn + s_r) * K + koff + s_lc * 8;
    unsigned short* dA0 = As0 + tid * 8;
    unsigned short* dA1 = dA0 + 8192;
    unsigned short* dB0 = Bs0 + tid * 8;
    unsigned short* dB1 = dB0 + 8192;

    // ---- Hoisted LDS read pointers (loop-invariant) ----
    // byte off = r*128 + (((kk*4+quad)^(r&7))*16), r thread-constant.
    const int ra0 = wm + colL, ra1 = wm + 16 + colL;
    const int rb0 = wn + colL, rb1 = wn + 16 + colL;
    const char* pA0[2][2]; const char* pA1[2][2];
    const char* pB0[2][2]; const char* pB1[2][2];
    #pragma unroll
    for (int kk = 0; kk < 2; ++kk) {
        int oa0 = ra0 * 128 + (((kk * 4 + quad) ^ (ra0 & 7)) * 16);
        int oa1 = ra1 * 128 + (((kk * 4 + quad) ^ (ra1 & 7)) * 16);
        int ob0 = rb0 * 128 + (((kk * 4 + quad) ^ (rb0 & 7)) * 16);
        int ob1 = rb1 * 128 + (((kk * 4 + quad) ^ (rb1 & 7)) * 16);
        pA0[kk][0] = (const char*)As0 + oa0;  pA0[kk][1] = (const char*)As0 + oa1;
        pA1[kk][0] = pA0[kk][0] + 16384;      pA1[kk][1] = pA0[kk][1] + 16384;
        pB0[kk][0] = (const char*)Bs0 + ob0;  pB0[kk][1] = (const char*)Bs0 + ob1;
        pB1[kk][0] = pB0[kk][0] + 16384;      pB1[kk][1] = pB0[kk][1] + 16384;
    }

    stage16(gA, dA0);               // prologue: tile 0 -> buf 0
    stage16(gB, dB0);

    auto body = [&](int t, const char* const pA[2][2], const char* const pB[2][2],
                    unsigned short* dAn, unsigned short* dBn) {
        if (t + 1 < nt) {
            const int k0 = (t + 1) << 6;
            stage16(gA + k0, dAn);
            stage16(gB + k0, dBn);
            asm volatile("s_waitcnt vmcnt(2)" ::: "memory"); // tile t ready
        } else {
            asm volatile("s_waitcnt vmcnt(0)" ::: "memory");
        }
        __builtin_amdgcn_s_barrier();        // raw: no vmcnt drain
        __builtin_amdgcn_sched_barrier(0);

        #pragma unroll
        for (int kk = 0; kk < 2; ++kk) {
            short8 af0 = *(const short8*)pA[kk][0];
            short8 af1 = *(const short8*)pA[kk][1];
            short8 bf0 = *(const short8*)pB[kk][0];
            short8 bf1 = *(const short8*)pB[kk][1];
            acc[0][0] = __builtin_amdgcn_mfma_f32_16x16x32_bf16(af0, bf0, acc[0][0], 0, 0, 0);
            acc[0][1] = __builtin_amdgcn_mfma_f32_16x16x32_bf16(af0, bf1, acc[0][1], 0, 0, 0);
            acc[1][0] = __builtin_amdgcn_mfma_f32_16x16x32_bf16(af1, bf0, acc[1][0], 0, 0, 0);
            acc[1][1] = __builtin_amdgcn_mfma_f32_16x16x32_bf16(af1, bf1, acc[1][1], 0, 0, 0);
        }
        __builtin_amdgcn_sched_barrier(0);
        asm volatile("" ::: "memory");
        __builtin_amdgcn_s_barrier();        // reads of this buf done before overwrite
    };

    for (int t = 0; t < nt; t += 2) {
        body(t,     pA0, pB0, dA1, dB1);     // buf 0, prefetch -> buf 1
        body(t + 1, pA1, pB1, dA0, dB0);     // buf 1, prefetch -> buf 0
    }

    if constexpr (MODE == 0 || MODE == 2) {
        float* Cw = (MODE == 2) ? C + (size_t)blockIdx.z * M * N : C;
        #pragma unroll
        for (int i = 0; i < 2; ++i)
            #pragma unroll
            for (int j = 0; j < 2; ++j)
                #pragma unroll
                for (int rr = 0; rr < 4; ++rr) {
                    int row = bm + wm + i * 16 + quad * 4 + rr;
                    int cc2 = bn + wn + j * 16 + colL;
                    Cw[(size_t)row * N + cc2] = acc[i][j][rr];
                }
    } else {
        if (bn < QK_N) {
            // ---------- Phase A: RMSNorm, acc -> bf16 xnL, acc dies ----------
            __shared__ float sums[4][128];
            unsigned short* xnL = smem;     // overlay: [d][row], stride 132

            float p[2][4];
            #pragma unroll
            for (int i = 0; i < 2; ++i)
                #pragma unroll
                for (int rr = 0; rr < 4; ++rr) {
                    float sv = 0.f;
                    #pragma unroll
                    for (int j = 0; j < 2; ++j)
                        sv = fmaf(acc[i][j][rr], acc[i][j][rr], sv);
                    p[i][rr] = sv;
                }
            #pragma unroll
            for (int off = 1; off < 16; off <<= 1)
                #pragma unroll
                for (int i = 0; i < 2; ++i)
                    #pragma unroll
                    for (int rr = 0; rr < 4; ++rr)
                        p[i][rr] += __shfl_xor(p[i][rr], off, 64);
            if (colL == 0) {
                #pragma unroll
                for (int i = 0; i < 2; ++i)
                    #pragma unroll
                    for (int rr = 0; rr < 4; ++rr)
                        sums[wc][wm + i * 16 + quad * 4 + rr] = p[i][rr];
            }
            __syncthreads();

            float inv_r[2][4];
            #pragma unroll
            for (int i = 0; i < 2; ++i)
                #pragma unroll
                for (int rr = 0; rr < 4; ++rr) {
                    int row = wm + i * 16 + quad * 4 + rr;
                    float tot = (sums[0][row] + sums[1][row]) + (sums[2][row] + sums[3][row]);
                    inv_r[i][rr] = rsqrtf(tot * (1.0f / HEAD_DIM) + EPS_);
                }

            const float* nw = (bn < Q_SIZE) ? qw : kw;
            float wv[2];
            #pragma unroll
            for (int j = 0; j < 2; ++j)
                wv[j] = nw[wn + j * 16 + colL];

            #pragma unroll
            for (int i = 0; i < 2; ++i)
                #pragma unroll
                for (int j = 0; j < 2; ++j) {
                    ushort4 pk;
                    pk.x = f2bf(acc[i][j][0] * inv_r[i][0] * wv[j]);
                    pk.y = f2bf(acc[i][j][1] * inv_r[i][1] * wv[j]);
                    pk.z = f2bf(acc[i][j][2] * inv_r[i][2] * wv[j]);
                    pk.w = f2bf(acc[i][j][3] * inv_r[i][3] * wv[j]);
                    int d = wn + j * 16 + colL;
                    *(ushort4*)&xnL[d * 132 + wm + i * 16 + quad * 4] = pk;
                }
            __syncthreads();
            // ---------- Phase B: RoPE from LDS only (no acc liveness) ----------
            // 1024 threads: thread -> (row r = tid>>3, freq octant oct = tid&7);
            // 8 sincos/thread, each produces BOTH d and d+64; ushort4 stores.
            {
                const int r = tid >> 3;
                const int oct = tid & 7;
                const float pos = (float)positions[bm + r];
                const bool is_q = (bn < Q_SIZE);
                const float l2r = 13.287712379549449f / 64.0f;
                const float sc = 0.08838834764831845f;
                unsigned short* rowp;
                if (is_q) rowp = Qb + (size_t)(bm + r) * Q_SIZE + (bn >> 7) * HEAD_DIM;
                else      rowp = Kb + ((size_t)((bn - Q_SIZE) >> 7) * T_SEQ + bm + r) * HEAD_DIM;

                #pragma unroll
                for (int f4 = 0; f4 < 8; f4 += 4) {
                    ushort4 lo, hi;
                    #pragma unroll
                    for (int e = 0; e < 4; ++e) {
                        int f = oct * 8 + f4 + e;
                        float x1 = b2f(xnL[f * 132 + r]);          // d = f
                        float x2 = b2f(xnL[(f + 64) * 132 + r]);   // d = f+64
                        float sv, cv;
                        __sincosf(pos * exp2f(-(float)f * l2r), &sv, &cv);
                        float olo = fmaf(x1, cv, -x2 * sv);
                        float ohi = fmaf(x2, cv,  x1 * sv);
                        if (is_q) { olo *= sc; ohi *= sc; }
                        ((unsigned short*)&lo)[e] = f2bf(olo);
                        ((unsigned short*)&hi)[e] = f2bf(ohi);
                    }
                    *(ushort4*)(rowp + oct * 8 + f4)      = lo;
                    *(ushort4*)(rowp + 64 + oct * 8 + f4) = hi;
                }
            }
        } else {
            const int kvh = (bn - QK_N) >> 7;
            #pragma unroll
            for (int i = 0; i < 2; ++i)
                #pragma unroll
                for (int j = 0; j < 2; ++j) {
                    int d = wn + j * 16 + colL;
                    int tok = bm + wm + i * 16 + quad * 4;
                    ushort4 o;
                    o.x = f2bf(acc[i][j][0]); o.y = f2bf(acc[i][j][1]);
                    o.z = f2bf(acc[i][j][2]); o.w = f2bf(acc[i][j][3]);
                    *(ushort4*)&Vt[((size_t)kvh * HEAD_DIM + d) * T_SEQ + tok] = o;
                }
        }
    }
}

// ---------------------------------------------------------------------------
// combine_o: out = p0 + p1 (fp32, 4M elements). ~32 MB read + 16 MB write.
// ---------------------------------------------------------------------------
__global__ __launch_bounds__(256) void combine_o(
    const float* __restrict__ pOp, float* __restrict__ out)
{
    const size_t i = (size_t)blockIdx.x * 256 + threadIdx.x;   // float4 index
    const float4* p0 = (const float4*)pOp;
    const float4* p1 = (const float4*)(pOp + (size_t)T_SEQ * Q_SIZE);
    float4 a = p0[i], b = p1[i];
    float4 o;
    o.x = a.x + b.x; o.y = a.y + b.y; o.z = a.z + b.z; o.w = a.w + b.w;
    ((float4*)out)[i] = o;
}

// ---------------------------------------------------------------------------
// Flash attention, R18 structure (BK=32, counted vmcnt + raw barriers, all
// LDS read addresses hoisted, unit loop unrolled by 2) — unchanged.
// ---------------------------------------------------------------------------
#define BQ 64
#define BK 32

__global__ __launch_bounds__(256) void attn_mfma(
    const unsigned short* __restrict__ Qb, const unsigned short* __restrict__ Kb,
    const unsigned short* __restrict__ Vt, unsigned short* __restrict__ ctxb,
    float* __restrict__ partO, float* __restrict__ partL)
{
    const int h = blockIdx.y;
    int qt, ch;
    {
        int x = blockIdx.x;
        if (x < 16) { qt = 16 + x; ch = 0; }
        else {
            int p = (x - 16) >> 1;
            if (((x - 16) & 1) == 0) { qt = 15 - p; ch = 0; }
            else                     { qt = 31 - p; ch = 1; }
        }
    }
    const int nch = (qt >= 16) ? 2 : 1;
    // units are BK=32 steps; a 1024-token chunk is 32 units. Always EVEN.
    const int units = (ch == 0) ? ((qt + 1 < 16) ? 2 * (qt + 1) : 32)
                                : (2 * (qt + 1) - 32);
    const int q0 = qt * BQ;
    const int kv = h >> 1;
    const int tid = threadIdx.x;
    const int w = tid >> 6;
    const int lane = tid & 63;
    const int col = lane & 15;
    const int quad = lane >> 4;

    __shared__ unsigned short Ks[2][32 * 128];   // 16 KB
    __shared__ unsigned short Vs[2][144 * 32];   // 18 KB (rows 128..143: ones/zeros)
    __shared__ unsigned short Ps[4][16][40];     // 5 KB (stride 40: 2-way banks)

    {
        int x = tid * 2;                          // ones region: 16 rows x 32 tok
        unsigned short vv = (x < 32) ? (unsigned short)0x3F80 : (unsigned short)0;
        ushort2 o = {vv, vv};
        *(ushort2*)&Vs[0][128 * 32 + x] = o;
        *(ushort2*)&Vs[1][128 * 32 + x] = o;
    }
    asm volatile("s_waitcnt lgkmcnt(0)" ::: "memory");  // ones visible pre-barrier

    short8 qf[4];
    {
        const unsigned short* qp = Qb + (size_t)(q0 + w * 16 + col) * Q_SIZE + h * HEAD_DIM;
        #pragma unroll
        for (int c = 0; c < 4; ++c)
            qf[c] = *(const short8*)(qp + c * 32 + quad * 8);
    }

    // Staging ptrs: K tile 32x128 = 512 chunks; V tile 128x32 = 512 chunks.
    const unsigned short* kg[2];
    const unsigned short* vg[2];
    #pragma unroll
    for (int it = 0; it < 2; ++it) {
        int s = it * 256 + tid;
        int kr = s >> 4, kp = s & 15, kj = kp ^ (kr & 15);
        kg[it] = Kb + (size_t)kv * T_SEQ * HEAD_DIM + kr * HEAD_DIM + kj * 8;
        int vr = s >> 2, vp = s & 3, vj = vp ^ ((vr >> 1) & 3);
        vg[it] = Vt + (size_t)kv * HEAD_DIM * T_SEQ + (size_t)vr * T_SEQ + vj * 8;
    }

    // ---- Hoisted per-thread LDS read bases (loop-invariant) ----
    const int kconst = col * 256;                         // bytes
    const char* k00 = (const char*)Ks[0] + kconst + (((0 * 4 + quad) ^ col) * 16);
    const char* k01 = (const char*)Ks[0] + kconst + (((1 * 4 + quad) ^ col) * 16);
    const char* k02 = (const char*)Ks[0] + kconst + (((2 * 4 + quad) ^ col) * 16);
    const char* k03 = (const char*)Ks[0] + kconst + (((3 * 4 + quad) ^ col) * 16);
    const char* k10 = (const char*)Ks[1] + kconst + (((0 * 4 + quad) ^ col) * 16);
    const char* k11 = (const char*)Ks[1] + kconst + (((1 * 4 + quad) ^ col) * 16);
    const char* k12 = (const char*)Ks[1] + kconst + (((2 * 4 + quad) ^ col) * 16);
    const char* k13 = (const char*)Ks[1] + kconst + (((3 * 4 + quad) ^ col) * 16);
    const int vconst = col * 64 + ((quad ^ ((col >> 1) & 3)) * 16);   // bytes
    const char* v0 = (const char*)Vs[0] + vconst;
    const char* v1 = (const char*)Vs[1] + vconst;
    char* psw = (char*)&Ps[w][col][quad * 4];             // write base (+cb*32 B)
    const char* psr = (const char*)&Ps[w][col][quad * 8]; // read base

    floatx4 Ob[9];
    #pragma unroll
    for (int cb = 0; cb < 9; ++cb) Ob[cb] = (floatx4){0.f, 0.f, 0.f, 0.f};

    const int wave_qmin = q0 + w * 16;
    const int wave_qmax = wave_qmin + 15;
    const int tok_base = ch * 1024;

    #pragma unroll
    for (int it = 0; it < 2; ++it) {
        stage16(kg[it] + (size_t)tok_base * HEAD_DIM, &Ks[0][(it * 256 + w * 64) * 8]);
        stage16(vg[it] + tok_base, &Vs[0][(it * 256 + w * 64) * 8]);
    }

    auto body = [&](int u, const char* kb0, const char* kb1, const char* kb2,
                    const char* kb3, const char* vb,
                    unsigned short* KsN, unsigned short* VsN) {
        const int t0 = tok_base + u * BK;
        if (u + 1 < units) {
            const int tn = t0 + BK;
            #pragma unroll
            for (int it = 0; it < 2; ++it) {
                stage16(kg[it] + (size_t)tn * HEAD_DIM, &KsN[(it * 256 + w * 64) * 8]);
                stage16(vg[it] + tn, &VsN[(it * 256 + w * 64) * 8]);
            }
            asm volatile("s_waitcnt vmcnt(4)" ::: "memory");   // tile u ready
        } else {
            asm volatile("s_waitcnt vmcnt(0)" ::: "memory");
        }
        __builtin_amdgcn_s_barrier();          // raw: prefetch stays in flight
        __builtin_amdgcn_sched_barrier(0);

        if (t0 <= wave_qmax) {
            floatx4 S[2];
            #pragma unroll
            for (int cb = 0; cb < 2; ++cb) {
                floatx4 a = (floatx4){0.f, 0.f, 0.f, 0.f};
                a = __builtin_amdgcn_mfma_f32_16x16x32_bf16(*(const short8*)(kb0 + cb * 4096), qf[0], a, 0, 0, 0);
                a = __builtin_amdgcn_mfma_f32_16x16x32_bf16(*(const short8*)(kb1 + cb * 4096), qf[1], a, 0, 0, 0);
                a = __builtin_amdgcn_mfma_f32_16x16x32_bf16(*(const short8*)(kb2 + cb * 4096), qf[2], a, 0, 0, 0);
                a = __builtin_amdgcn_mfma_f32_16x16x32_bf16(*(const short8*)(kb3 + cb * 4096), qf[3], a, 0, 0, 0);
                S[cb] = a;
            }

            const int qr = q0 + w * 16 + col;
            if (t0 + 31 <= wave_qmin) {
                #pragma unroll
                for (int cb = 0; cb < 2; ++cb) {
                    ushort4 pk;
                    pk.x = f2bf(__expf(S[cb][0])); pk.y = f2bf(__expf(S[cb][1]));
                    pk.z = f2bf(__expf(S[cb][2])); pk.w = f2bf(__expf(S[cb][3]));
                    *(ushort4*)(psw + cb * 32) = pk;
                }
            } else {
                #pragma unroll
                for (int cb = 0; cb < 2; ++cb) {
                    int kt = t0 + cb * 16 + quad * 4;
                    ushort4 pk;
                    pk.x = (kt + 0 <= qr) ? f2bf(__expf(S[cb][0])) : (unsigned short)0;
                    pk.y = (kt + 1 <= qr) ? f2bf(__expf(S[cb][1])) : (unsigned short)0;
                    pk.z = (kt + 2 <= qr) ? f2bf(__expf(S[cb][2])) : (unsigned short)0;
                    pk.w = (kt + 3 <= qr) ? f2bf(__expf(S[cb][3])) : (unsigned short)0;
                    *(ushort4*)(psw + cb * 32) = pk;
                }
            }

            short8 pf = *(const short8*)psr;
            #pragma unroll
            for (int cb = 0; cb < 9; ++cb)
                Ob[cb] = __builtin_amdgcn_mfma_f32_16x16x32_bf16(
                    pf, *(const short8*)(vb + cb * 1024), Ob[cb], 0, 0, 0);
        }
        __builtin_amdgcn_sched_barrier(0);
        asm volatile("" ::: "memory");
        __builtin_amdgcn_s_barrier();          // reads of this buf done before overwrite
    };

    for (int u = 0; u < units; u += 2) {
        body(u,     k00, k01, k02, k03, v0, Ks[1], Vs[1]);   // buf 0, prefetch -> 1
        body(u + 1, k10, k11, k12, k13, v1, Ks[0], Vs[0]);   // buf 1, prefetch -> 0
    }

    if (nch == 1) {
        #pragma unroll
        for (int r = 0; r < 4; ++r) {
            float l = __shfl(Ob[8][r], lane & 48);
            float rl = 1.0f / l;
            const int qrow = q0 + w * 16 + quad * 4 + r;
            #pragma unroll
            for (int cb = 0; cb < 8; ++cb)
                ctxb[(size_t)qrow * Q_SIZE + h * HEAD_DIM + cb * 16 + col] = f2bf(Ob[cb][r] * rl);
        }
    } else {
        const int slot = (h * 16 + (qt - 16)) * 2 + ch;
        float* po = partO + (size_t)slot * (BQ * HEAD_DIM);
        #pragma unroll
        for (int cb = 0; cb < 8; ++cb)
            #pragma unroll
            for (int r = 0; r < 4; ++r)
                po[(w * 16 + quad * 4 + r) * HEAD_DIM + cb * 16 + col] = Ob[cb][r];
        if (col == 0) {
            #pragma unroll
            for (int r = 0; r < 4; ++r)
                partL[slot * BQ + w * 16 + quad * 4 + r] = Ob[8][r];
        }
    }
}

// ---------------------------------------------------------------------------
// Combine: ctx[qt>=16] = (O0 + O1) / (l0 + l1).
// ---------------------------------------------------------------------------
__global__ __launch_bounds__(256) void combine(
    const float* __restrict__ partO, const float* __restrict__ partL,
    unsigned short* __restrict__ ctxb)
{
    const int h = blockIdx.x >> 4;
    const int qi = blockIdx.x & 15;
    const int q0 = (16 + qi) * 64;
    const int slot0 = (h * 16 + qi) * 2;
    const int tid = threadIdx.x;
    const int row = tid >> 2;
    const int seg = tid & 3;

    const float l = partL[slot0 * 64 + row] + partL[(slot0 + 1) * 64 + row];
    const float rl = 1.0f / l;
    const float* p0 = partO + (size_t)slot0 * 8192 + row * 128 + seg * 32;
    const float* p1 = p0 + 8192;
    unsigned short* dst = ctxb + (size_t)(q0 + row) * Q_SIZE + h * HEAD_DIM + seg * 32;
    #pragma unroll
    for (int m = 0; m < 8; ++m) {
        float4 a = *(const float4*)(p0 + m * 4);
        float4 b = *(const float4*)(p1 + m * 4);
        ushort4 o;
        o.x = f2bf((a.x + b.x) * rl); o.y = f2bf((a.y + b.y) * rl);
        o.z = f2bf((a.z + b.z) * rl); o.w = f2bf((a.w + b.w) * rl);
        *(ushort4*)(dst + m * 4) = o;
    }
}

// ---------------------------------------------------------------------------
extern "C" void kernel_launch(void* const* d_in, const int* in_sizes, int n_in,
                              void* d_out, int out_size, void* d_ws, size_t ws_size,
                              hipStream_t stream)
{
    const int*   positions = (const int*)d_in[0];
    const float* hidden    = (const float*)d_in[1];
    const float* qkv_w     = (const float*)d_in[2];
    const float* q_norm_w  = (const float*)d_in[3];
    const float* k_norm_w  = (const float*)d_in[4];
    const float* o_w       = (const float*)d_in[5];
    float* out = (float*)d_out;

    const size_t MB = 1024 * 1024;
    char* ws = (char*)d_ws;
    unsigned short* obf  = (unsigned short*)ws;                 // [0,8)   whole run
    unsigned short* hbf  = (unsigned short*)(ws + 8 * MB);      // [8,16)  dead after QKV GEMM
    unsigned short* wbf  = (unsigned short*)(ws + 16 * MB);     // [16,32) dead after QKV GEMM
    unsigned short* Vt   = (unsigned short*)(ws + 32 * MB);     // [32,36) dead after attn
    unsigned short* Qb   = (unsigned short*)(ws + 36 * MB);     // [36,44) dead after attn
    unsigned short* Kb   = (unsigned short*)(ws + 44 * MB);     // [44,48) dead after attn
    unsigned short* ctxb = (unsigned short*)(ws + 48 * MB);     // [48,56)
    float* partL         = (float*)(ws + 8 * MB);               // [8,8.125) over dead hbf
    float* partO         = (float*)(ws + 16 * MB);              // [16,32) over dead wbf (16 MB)
    // O-proj split-K partials (2 x 16 MB fp32) over regions dead after
    // attn+combine: [8,40) covers hbf/wbf/partO/partL/Vt/Qb-start.
    float* pOp           = (float*)(ws + 8 * MB);               // [8,40)

    convert_all<<<(H4 + W4 + O4 + 255) / 256, 256, 0, stream>>>(
        hidden, qkv_w, o_w, hbf, wbf, obf);
    gemm_nt_bf16<1><<<dim3(QKV_N / 128, T_SEQ / 128), 1024, 0, stream>>>(
        hbf, wbf, nullptr, Qb, Kb, Vt, positions, q_norm_w, k_norm_w,
        T_SEQ, QKV_N, HIDDEN_);
    attn_mfma<<<dim3(48, NUM_HEADS), 256, 0, stream>>>(Qb, Kb, Vt, ctxb, partO, partL);
    combine<<<256, 256, 0, stream>>>(partO, partL, ctxb);
    gemm_nt_bf16<2><<<dim3(Q_SIZE / 128, T_SEQ / 128, 2), 1024, 0, stream>>>(
        ctxb, obf, pOp, nullptr, nullptr, nullptr, nullptr, nullptr, nullptr,
        T_SEQ, Q_SIZE, HIDDEN_);
    combine_o<<<(T_SEQ * Q_SIZE / 4) / 256, 256, 0, stream>>>(pOp, out);
}